// Round 7
// baseline (250.757 us; speedup 1.0000x reference)
//
#include <hip/hip_runtime.h>
#include <math.h>

#define B 8
#define S 4096
#define H 2048
#define LSYM 8
#define EMB 64
#define SPLIT 64
#define CHUNK (S / SPLIT)   // 64 rows per slab
#define QPB 4               // mega blocks per batch

// ---------------- Kernel 1: partial pooling over S, contiguous slabs, 8 acc chains ----------------
__global__ __launch_bounds__(256) void pool_partial(const float* __restrict__ hid,
                                                    float* __restrict__ part) {
    const int sp = blockIdx.x;          // 0..SPLIT-1
    const int b  = blockIdx.y;
    const int t  = threadIdx.x;
    const float* slab = hid + (size_t)b * S * H + (size_t)sp * CHUNK * H;
    const int iters = CHUNK * (H / 1024);   // 128
    float4 a[8];
#pragma unroll
    for (int k = 0; k < 8; ++k) a[k] = make_float4(0.f, 0.f, 0.f, 0.f);
    for (int i = 0; i < iters; i += 8) {
#pragma unroll
        for (int k = 0; k < 8; ++k) {
            const float4 v = *reinterpret_cast<const float4*>(slab + (size_t)(i + k) * 1024 + t * 4);
            a[k].x += v.x; a[k].y += v.y; a[k].z += v.z; a[k].w += v.w;
        }
    }
    // even i -> h = t*4 ; odd i -> h = 1024 + t*4
    float4 e, o;
    e.x = a[0].x + a[2].x + a[4].x + a[6].x;  e.y = a[0].y + a[2].y + a[4].y + a[6].y;
    e.z = a[0].z + a[2].z + a[4].z + a[6].z;  e.w = a[0].w + a[2].w + a[4].w + a[6].w;
    o.x = a[1].x + a[3].x + a[5].x + a[7].x;  o.y = a[1].y + a[3].y + a[5].y + a[7].y;
    o.z = a[1].z + a[3].z + a[5].z + a[7].z;  o.w = a[1].w + a[3].w + a[5].w + a[7].w;
    float* dst = part + ((size_t)sp * B + b) * H;
    *reinterpret_cast<float4*>(dst + t * 4)        = e;
    *reinterpret_cast<float4*>(dst + 1024 + t * 4) = o;
}

// ---------------- Kernel 2: mega MLP (32 blocks x 1024 threads; 4 blocks per batch) ----------------
// Each block: reduce part -> pooled(LDS); enc1 (dup); middle chain (dup); dec2 quarter (disjoint).
__device__ __forceinline__ float block_sum1024(float x, float* red16) {
    const int t = threadIdx.x;
    const int lane = t & 63, wv = t >> 6;
    for (int off = 32; off; off >>= 1) x += __shfl_xor(x, off, 64);
    if (lane == 0) red16[wv] = x;
    __syncthreads();
    float r = 0.f;
#pragma unroll
    for (int i = 0; i < 16; ++i) r += red16[i];
    __syncthreads();
    return r;
}

__global__ __launch_bounds__(1024) void mega(
    const float* __restrict__ part, const float* __restrict__ gu,
    const float* __restrict__ ew1, const float* __restrict__ eb1,
    const float* __restrict__ g1,  const float* __restrict__ bb1,
    const float* __restrict__ ew2, const float* __restrict__ eb2,
    const float* __restrict__ emb_tab,
    const float* __restrict__ dw1, const float* __restrict__ db1,
    const float* __restrict__ g2,  const float* __restrict__ bb2,
    const float* __restrict__ dw2, const float* __restrict__ db2,
    float* __restrict__ dec_sc) {
    __shared__ float pooled[H];        // 8 KB
    __shared__ float red16[16];
    __shared__ float out1s[256];
    __shared__ float hsm[256];
    __shared__ float es[LSYM * EMB];   // 512
    __shared__ float hs2s[256];

    const int blk = blockIdx.x;
    const int b = blk >> 2, q = blk & (QPB - 1);
    const int t = threadIdx.x;
    const int wv = t >> 6, lane = t & 63;

    // ---- phase 0: reduce part[sp][b][:] over sp -> pooled mean (LDS)
    if (t < H / 4) {
        const float4* pp = reinterpret_cast<const float4*>(part);
        float4 acc = {0.f, 0.f, 0.f, 0.f};
#pragma unroll 4
        for (int sp = 0; sp < SPLIT; ++sp) {
            const float4 v = pp[((size_t)sp * B + b) * (H / 4) + t];
            acc.x += v.x; acc.y += v.y; acc.z += v.z; acc.w += v.w;
        }
        const float inv = 1.0f / (float)S;
        acc.x *= inv; acc.y *= inv; acc.z *= inv; acc.w *= inv;
        *reinterpret_cast<float4*>(&pooled[t * 4]) = acc;
    }
    __syncthreads();

    // ---- phase 1: enc1 — 16 waves x 16 outputs, wave-dot over H
#pragma unroll
    for (int k = 0; k < 16; ++k) {
        const int tt = wv * 16 + k;
        const float4* wrow = reinterpret_cast<const float4*>(ew1 + (size_t)tt * H);
        float acc = 0.f;
#pragma unroll
        for (int i = 0; i < 8; ++i) {
            const float4 w = wrow[lane + 64 * i];
            const float4 p = *reinterpret_cast<const float4*>(&pooled[(lane + 64 * i) * 4]);
            acc += w.x * p.x + w.y * p.y + w.z * p.z + w.w * p.w;
        }
        for (int off = 32; off; off >>= 1) acc += __shfl_xor(acc, off, 64);
        if (lane == 0) out1s[tt] = acc + eb1[tt];
    }
    __syncthreads();

    // ---- phase 2: middle chain (threads t<256 active; barriers top-level)
    float x0 = (t < 256) ? out1s[t] : 0.f;
    const float m1 = block_sum1024(x0, red16) * (1.0f / 256.0f);
    const float d1 = (t < 256) ? (x0 - m1) : 0.f;
    const float v1 = block_sum1024(d1 * d1, red16) * (1.0f / 256.0f);
    if (t < 256) {
        float x = d1 * rsqrtf(v1 + 1e-5f) * g1[t] + bb1[t];
        x = 0.5f * x * (1.0f + erff(x * 0.70710678118654752f));
        hsm[t] = x;
    }
    __syncthreads();

    if (t < 256) {
        float a2 = eb2[t];
        const float* w2row = ew2 + t * 256;
        for (int k = 0; k < 256; k += 4) {
            const float4 w = *reinterpret_cast<const float4*>(w2row + k);
            a2 += w.x * hsm[k] + w.y * hsm[k + 1] + w.z * hsm[k + 2] + w.w * hsm[k + 3];
        }
        const float u = gu[b * 256 + t];
        const float z = a2 - logf(-logf(u));
        // per-l argmax over V=32 within 32-lane group (first-max tiebreak)
        int   bi = t & 31;
        float bz = z;
        for (int off = 16; off; off >>= 1) {
            const float oz = __shfl_xor(bz, off, 32);
            const int   oi = __shfl_xor(bi, off, 32);
            if (oz > bz || (oz == bz && oi < bi)) { bz = oz; bi = oi; }
        }
        const int l = t >> 5, v32 = t & 31;
        es[l * EMB + v32]      = emb_tab[bi * EMB + v32];
        es[l * EMB + 32 + v32] = emb_tab[bi * EMB + 32 + v32];
    }
    __syncthreads();

    float a3 = 0.f;
    if (t < 256) {
        a3 = db1[t];
        const float* d1row = dw1 + t * (LSYM * EMB);
        for (int k = 0; k < LSYM * EMB; k += 4) {
            const float4 w = *reinterpret_cast<const float4*>(d1row + k);
            a3 += w.x * es[k] + w.y * es[k + 1] + w.z * es[k + 2] + w.w * es[k + 3];
        }
    }
    const float m2 = block_sum1024((t < 256) ? a3 : 0.f, red16) * (1.0f / 256.0f);
    const float d2 = (t < 256) ? (a3 - m2) : 0.f;
    const float v2 = block_sum1024(d2 * d2, red16) * (1.0f / 256.0f);
    if (t < 256) {
        float y = d2 * rsqrtf(v2 + 1e-5f) * g2[t] + bb2[t];
        y = 0.5f * y * (1.0f + erff(y * 0.70710678118654752f));
        hs2s[t] = y;
    }
    __syncthreads();

    // ---- phase 3: dec2 quarter — 16 waves x 32 outputs, wave-dot over 256
    const float4 hvec = *reinterpret_cast<const float4*>(&hs2s[lane * 4]);
#pragma unroll
    for (int k = 0; k < 32; ++k) {
        const int j = q * 512 + wv * 32 + k;
        const float4 w = reinterpret_cast<const float4*>(dw2 + (size_t)j * 256)[lane];
        float acc = w.x * hvec.x + w.y * hvec.y + w.z * hvec.z + w.w * hvec.w;
        for (int off = 32; off; off >>= 1) acc += __shfl_xor(acc, off, 64);
        if (lane == 0) dec_sc[b * 2048 + j] = 0.1f * (acc + db2[j]);
    }
}

// ---------------- Kernel 3: residual broadcast add (dv hoisted, plain stores) ----------------
__global__ __launch_bounds__(256) void residual_add(const float* __restrict__ hid,
                                                    const float* __restrict__ dec,
                                                    float* __restrict__ out) {
    const size_t tid0 = (size_t)blockIdx.x * 256 + threadIdx.x;   // < 2^19
    const int h4 = (int)(tid0 & (H / 4 - 1));
    const float4* __restrict__ hv4 = reinterpret_cast<const float4*>(hid);
    const float4* __restrict__ dv4 = reinterpret_cast<const float4*>(dec);
    float4* __restrict__ ov4 = reinterpret_cast<float4*>(out);
    size_t i = tid0;
#pragma unroll
    for (int b = 0; b < B; ++b) {
        const float4 dv = dv4[b * (H / 4) + h4];
#pragma unroll
        for (int r = 0; r < 4; ++r, i += (size_t)1 << 19) {
            const float4 hv = hv4[i];
            float4 o;
            o.x = hv.x + dv.x; o.y = hv.y + dv.y; o.z = hv.z + dv.z; o.w = hv.w + dv.w;
            ov4[i] = o;
        }
    }
}

extern "C" void kernel_launch(void* const* d_in, const int* in_sizes, int n_in,
                              void* d_out, int out_size, void* d_ws, size_t ws_size,
                              hipStream_t stream) {
    const float* hid   = (const float*)d_in[0];
    const float* gu    = (const float*)d_in[1];
    const float* ew1   = (const float*)d_in[2];
    const float* eb1   = (const float*)d_in[3];
    const float* g1    = (const float*)d_in[4];
    const float* bb1   = (const float*)d_in[5];
    const float* ew2   = (const float*)d_in[6];
    const float* eb2   = (const float*)d_in[7];
    const float* emb   = (const float*)d_in[8];
    const float* dw1   = (const float*)d_in[9];
    const float* db1   = (const float*)d_in[10];
    const float* g2    = (const float*)d_in[11];
    const float* bb2   = (const float*)d_in[12];
    const float* dw2   = (const float*)d_in[13];
    const float* db2   = (const float*)d_in[14];
    float* out = (float*)d_out;

    // workspace: [ part: SPLIT*B*H (4 MiB) | dec_sc: B*H (64 KB) ]
    float* part   = (float*)d_ws;
    float* dec_sc = part + (size_t)SPLIT * B * H;

    pool_partial<<<dim3(SPLIT, B), 256, 0, stream>>>(hid, part);
    mega<<<B * QPB, 1024, 0, stream>>>(part, gu, ew1, eb1, g1, bb1, ew2, eb2, emb,
                                       dw1, db1, g2, bb2, dw2, db2, dec_sc);
    residual_add<<<2048, 256, 0, stream>>>(hid, dec_sc, out);
}

// Round 8
// 221.725 us; speedup vs baseline: 1.1309x; 1.1309x over previous
//
#include <hip/hip_runtime.h>
#include <math.h>

#define B 8
#define S 4096
#define H 2048
#define LSYM 8
#define EMB 64
#define SPLIT 64
#define CHUNK (S / SPLIT)   // 64 rows per slab

// ---------------- Kernel 1: partial pooling over S (identical to R6) ----------------
__global__ __launch_bounds__(256) void pool_partial(const float* __restrict__ hid,
                                                    float* __restrict__ part) {
    const int sp = blockIdx.x;          // 0..SPLIT-1
    const int b  = blockIdx.y;
    const int t  = threadIdx.x;
    const float* slab = hid + (size_t)b * S * H + (size_t)sp * CHUNK * H;
    const int iters = CHUNK * (H / 1024);   // 128
    float4 a[8];
#pragma unroll
    for (int k = 0; k < 8; ++k) a[k] = make_float4(0.f, 0.f, 0.f, 0.f);
    for (int i = 0; i < iters; i += 8) {
#pragma unroll
        for (int k = 0; k < 8; ++k) {
            const float4 v = *reinterpret_cast<const float4*>(slab + (size_t)(i + k) * 1024 + t * 4);
            a[k].x += v.x; a[k].y += v.y; a[k].z += v.z; a[k].w += v.w;
        }
    }
    float4 e, o;
    e.x = a[0].x + a[2].x + a[4].x + a[6].x;  e.y = a[0].y + a[2].y + a[4].y + a[6].y;
    e.z = a[0].z + a[2].z + a[4].z + a[6].z;  e.w = a[0].w + a[2].w + a[4].w + a[6].w;
    o.x = a[1].x + a[3].x + a[5].x + a[7].x;  o.y = a[1].y + a[3].y + a[5].y + a[7].y;
    o.z = a[1].z + a[3].z + a[5].z + a[7].z;  o.w = a[1].w + a[3].w + a[5].w + a[7].w;
    float* dst = part + ((size_t)sp * B + b) * H;
    *reinterpret_cast<float4*>(dst + t * 4)        = e;
    *reinterpret_cast<float4*>(dst + 1024 + t * 4) = o;
}

// ---------------- Kernel 2: fused pool_reduce + enc1 ----------------
// 256 blocks x 256 threads: block (b, chunk) reduces part[:,b,:] into LDS pooled
// (512 KiB of L2-resident reads), then computes 8 enc1 outputs via wave-dots.
__global__ __launch_bounds__(256) void reduce_enc1(const float* __restrict__ part,
                                                   const float* __restrict__ ew1,
                                                   const float* __restrict__ eb1,
                                                   float* __restrict__ out1) {
    __shared__ float pooled[H];        // 8 KB
    const int bid   = blockIdx.x;
    const int b     = bid >> 5;        // 0..7
    const int chunk = bid & 31;        // 0..31
    const int t     = threadIdx.x;

    // phase 1: redundant reduce of part[:, b, :] -> pooled (mean)
    {
        const float4* pp = reinterpret_cast<const float4*>(part);
        float4 acc0 = {0.f, 0.f, 0.f, 0.f};
        float4 acc1 = {0.f, 0.f, 0.f, 0.f};
#pragma unroll 4
        for (int sp = 0; sp < SPLIT; ++sp) {
            const size_t base = ((size_t)sp * B + b) * (H / 4);
            const float4 v0 = pp[base + t];
            const float4 v1 = pp[base + t + 256];
            acc0.x += v0.x; acc0.y += v0.y; acc0.z += v0.z; acc0.w += v0.w;
            acc1.x += v1.x; acc1.y += v1.y; acc1.z += v1.z; acc1.w += v1.w;
        }
        const float inv = 1.0f / (float)S;
        acc0.x *= inv; acc0.y *= inv; acc0.z *= inv; acc0.w *= inv;
        acc1.x *= inv; acc1.y *= inv; acc1.z *= inv; acc1.w *= inv;
        *reinterpret_cast<float4*>(&pooled[t * 4])         = acc0;
        *reinterpret_cast<float4*>(&pooled[(t + 256) * 4]) = acc1;
    }
    __syncthreads();

    // phase 2: 4 waves x 2 outputs each
    const int wv = t >> 6, lane = t & 63;
#pragma unroll
    for (int k = 0; k < 2; ++k) {
        const int tt = chunk * 8 + wv * 2 + k;
        const float4* wrow = reinterpret_cast<const float4*>(ew1 + (size_t)tt * H);
        float acc = 0.f;
#pragma unroll
        for (int i = 0; i < 8; ++i) {
            const float4 w = wrow[lane + 64 * i];
            const float4 p = *reinterpret_cast<const float4*>(&pooled[(lane + 64 * i) * 4]);
            acc += w.x * p.x + w.y * p.y + w.z * p.z + w.w * p.w;
        }
        for (int off = 32; off; off >>= 1) acc += __shfl_xor(acc, off, 64);
        if (lane == 0) out1[b * 256 + tt] = acc + eb1[tt];
    }
}

// ---------------- Kernel 3: fused middle chain + dec2 ----------------
// 256 blocks x 256 threads: block (b, jc) redundantly runs the middle chain
// (ew2/dw1 L2-resident), then computes its disjoint 64 dec2 outputs.
__device__ __forceinline__ float block_sum256(float x, float* red) {
    const int t = threadIdx.x;
    red[t] = x;
    __syncthreads();
    for (int s = 128; s > 0; s >>= 1) {
        if (t < s) red[t] += red[t + s];
        __syncthreads();
    }
    const float r = red[0];
    __syncthreads();
    return r;
}

__global__ __launch_bounds__(256) void middle_dec2(
    const float* __restrict__ out1, const float* __restrict__ gu,
    const float* __restrict__ g1,  const float* __restrict__ bb1,
    const float* __restrict__ ew2, const float* __restrict__ eb2,
    const float* __restrict__ emb_tab,
    const float* __restrict__ dw1, const float* __restrict__ db1,
    const float* __restrict__ g2,  const float* __restrict__ bb2,
    const float* __restrict__ dw2, const float* __restrict__ db2,
    float* __restrict__ dec_sc) {
    __shared__ float red[256];
    __shared__ float hsm[256];
    __shared__ float es[LSYM * EMB];
    __shared__ float hs2s[256];

    const int bid = blockIdx.x;
    const int b   = bid >> 5;       // 0..7
    const int jc  = bid & 31;       // 0..31
    const int t   = threadIdx.x;

    // ---- middle chain (redundant per block)
    float acc = out1[b * 256 + t];
    {
        const float m = block_sum256(acc, red) * (1.0f / 256.0f);
        const float d = acc - m;
        const float v = block_sum256(d * d, red) * (1.0f / 256.0f);
        float x = d * rsqrtf(v + 1e-5f) * g1[t] + bb1[t];
        x = 0.5f * x * (1.0f + erff(x * 0.70710678118654752f));
        hsm[t] = x;
    }
    __syncthreads();

    {
        float a2 = eb2[t];
        const float* w2row = ew2 + t * 256;
        for (int k = 0; k < 256; k += 4) {
            const float4 w = *reinterpret_cast<const float4*>(w2row + k);
            a2 += w.x * hsm[k] + w.y * hsm[k + 1] + w.z * hsm[k + 2] + w.w * hsm[k + 3];
        }
        const float u = gu[b * 256 + t];
        const float z = a2 - logf(-logf(u));
        int   bi = t & 31;
        float bz = z;
        for (int off = 16; off; off >>= 1) {
            const float oz = __shfl_xor(bz, off, 32);
            const int   oi = __shfl_xor(bi, off, 32);
            if (oz > bz || (oz == bz && oi < bi)) { bz = oz; bi = oi; }
        }
        const int l = t >> 5, v32 = t & 31;
        es[l * EMB + v32]      = emb_tab[bi * EMB + v32];
        es[l * EMB + 32 + v32] = emb_tab[bi * EMB + 32 + v32];
    }
    __syncthreads();

    float a3 = db1[t];
    {
        const float* d1row = dw1 + t * (LSYM * EMB);
        for (int k = 0; k < LSYM * EMB; k += 4) {
            const float4 w = *reinterpret_cast<const float4*>(d1row + k);
            a3 += w.x * es[k] + w.y * es[k + 1] + w.z * es[k + 2] + w.w * es[k + 3];
        }
    }
    {
        const float m2 = block_sum256(a3, red) * (1.0f / 256.0f);
        const float dd = a3 - m2;
        const float vv = block_sum256(dd * dd, red) * (1.0f / 256.0f);
        float y = dd * rsqrtf(vv + 1e-5f) * g2[t] + bb2[t];
        y = 0.5f * y * (1.0f + erff(y * 0.70710678118654752f));
        hs2s[t] = y;
    }
    __syncthreads();

    // ---- dec2: 4 waves x 16 outputs each (disjoint across blocks)
    const int wv = t >> 6, lane = t & 63;
    const float4 hvec = *reinterpret_cast<const float4*>(&hs2s[lane * 4]);
#pragma unroll
    for (int k = 0; k < 16; ++k) {
        const int j = jc * 64 + wv * 16 + k;
        const float4 w = reinterpret_cast<const float4*>(dw2 + (size_t)j * 256)[lane];
        float a = w.x * hvec.x + w.y * hvec.y + w.z * hvec.z + w.w * hvec.w;
        for (int off = 32; off; off >>= 1) a += __shfl_xor(a, off, 64);
        if (lane == 0) dec_sc[b * 2048 + j] = 0.1f * (a + db2[j]);
    }
}

// ---------------- Kernel 4: residual broadcast add (identical to R6) ----------------
__global__ __launch_bounds__(256) void residual_add(const float* __restrict__ hid,
                                                    const float* __restrict__ dec,
                                                    float* __restrict__ out) {
    const size_t tid0 = (size_t)blockIdx.x * 256 + threadIdx.x;   // < 2^19
    const int h4 = (int)(tid0 & (H / 4 - 1));
    const float4* __restrict__ hv4 = reinterpret_cast<const float4*>(hid);
    const float4* __restrict__ dv4 = reinterpret_cast<const float4*>(dec);
    float4* __restrict__ ov4 = reinterpret_cast<float4*>(out);
    size_t i = tid0;
#pragma unroll
    for (int b = 0; b < B; ++b) {
        const float4 dv = dv4[b * (H / 4) + h4];
#pragma unroll
        for (int r = 0; r < 4; ++r, i += (size_t)1 << 19) {
            const float4 hv = hv4[i];
            float4 o;
            o.x = hv.x + dv.x; o.y = hv.y + dv.y; o.z = hv.z + dv.z; o.w = hv.w + dv.w;
            ov4[i] = o;
        }
    }
}

extern "C" void kernel_launch(void* const* d_in, const int* in_sizes, int n_in,
                              void* d_out, int out_size, void* d_ws, size_t ws_size,
                              hipStream_t stream) {
    const float* hid   = (const float*)d_in[0];
    const float* gu    = (const float*)d_in[1];
    const float* ew1   = (const float*)d_in[2];
    const float* eb1   = (const float*)d_in[3];
    const float* g1    = (const float*)d_in[4];
    const float* bb1   = (const float*)d_in[5];
    const float* ew2   = (const float*)d_in[6];
    const float* eb2   = (const float*)d_in[7];
    const float* emb   = (const float*)d_in[8];
    const float* dw1   = (const float*)d_in[9];
    const float* db1   = (const float*)d_in[10];
    const float* g2    = (const float*)d_in[11];
    const float* bb2   = (const float*)d_in[12];
    const float* dw2   = (const float*)d_in[13];
    const float* db2   = (const float*)d_in[14];
    float* out = (float*)d_out;

    // workspace: [ part: SPLIT*B*H (4 MiB) | dec_sc: B*H | out1: B*256 ]
    float* part   = (float*)d_ws;
    float* dec_sc = part + (size_t)SPLIT * B * H;
    float* out1   = dec_sc + (size_t)B * H;

    pool_partial<<<dim3(SPLIT, B), 256, 0, stream>>>(hid, part);
    reduce_enc1<<<256, 256, 0, stream>>>(part, ew1, eb1, out1);
    middle_dec2<<<256, 256, 0, stream>>>(out1, gu, g1, bb1, ew2, eb2, emb,
                                         dw1, db1, g2, bb2, dw2, db2, dec_sc);
    residual_add<<<2048, 256, 0, stream>>>(hid, dec_sc, out);
}

// Round 9
// 206.126 us; speedup vs baseline: 1.2165x; 1.0757x over previous
//
#include <hip/hip_runtime.h>
#include <math.h>

#define B 8
#define S 4096
#define H 2048
#define LSYM 8
#define EMB 64
#define SPLIT 64
#define CHUNK (S / SPLIT)   // 64 rows per slab

typedef float f32x4 __attribute__((ext_vector_type(4)));

// ---------------- Kernel 1: partial pooling over S (R6 + nt loads) ----------------
__global__ __launch_bounds__(256) void pool_partial(const float* __restrict__ hid,
                                                    float* __restrict__ part) {
    const int sp = blockIdx.x;          // 0..SPLIT-1
    const int b  = blockIdx.y;
    const int t  = threadIdx.x;
    const float* slab = hid + (size_t)b * S * H + (size_t)sp * CHUNK * H;
    const int iters = CHUNK * (H / 1024);   // 128
    f32x4 a[8];
#pragma unroll
    for (int k = 0; k < 8; ++k) a[k] = (f32x4)(0.f);
    for (int i = 0; i < iters; i += 8) {
#pragma unroll
        for (int k = 0; k < 8; ++k) {
            const f32x4 v = __builtin_nontemporal_load(
                reinterpret_cast<const f32x4*>(slab + (size_t)(i + k) * 1024 + t * 4));
            a[k] += v;
        }
    }
    // even i -> h = t*4 ; odd i -> h = 1024 + t*4
    const f32x4 e = a[0] + a[2] + a[4] + a[6];
    const f32x4 o = a[1] + a[3] + a[5] + a[7];
    float* dst = part + ((size_t)sp * B + b) * H;
    *reinterpret_cast<f32x4*>(dst + t * 4)        = e;
    *reinterpret_cast<f32x4*>(dst + 1024 + t * 4) = o;
}

// ---------------- Kernel 2: reduce partials -> pooled mean (identical to R6) ----------------
__global__ __launch_bounds__(256) void pool_reduce(const float* __restrict__ part,
                                                   float* __restrict__ pooled) {
    const int i4 = blockIdx.x * 256 + threadIdx.x;
    if (i4 >= B * H / 4) return;
    float4 acc = {0.f, 0.f, 0.f, 0.f};
    for (int sp = 0; sp < SPLIT; ++sp) {
        const float4 v = *reinterpret_cast<const float4*>(part + (size_t)sp * B * H + (size_t)i4 * 4);
        acc.x += v.x; acc.y += v.y; acc.z += v.z; acc.w += v.w;
    }
    const float inv = 1.0f / (float)S;
    acc.x *= inv; acc.y *= inv; acc.z *= inv; acc.w *= inv;
    *reinterpret_cast<float4*>(pooled + (size_t)i4 * 4) = acc;
}

// ---------------- Kernel 3a: enc layer 1 matvec (identical to R6) ----------------
__global__ __launch_bounds__(256) void enc1_matvec(const float* __restrict__ pooled,
                                                   const float* __restrict__ ew1,
                                                   const float* __restrict__ eb1,
                                                   float* __restrict__ out1) {
    const int wv   = (blockIdx.x * 256 + threadIdx.x) >> 6;
    const int lane = threadIdx.x & 63;
    const int b = wv >> 8, t = wv & 255;
    const float4* wrow = reinterpret_cast<const float4*>(ew1 + (size_t)t * H);
    const float4* prow = reinterpret_cast<const float4*>(pooled + b * H);
    float acc = 0.f;
#pragma unroll
    for (int i = 0; i < 8; ++i) {
        const float4 w = wrow[lane + 64 * i];
        const float4 p = prow[lane + 64 * i];
        acc += w.x * p.x + w.y * p.y + w.z * p.z + w.w * p.w;
    }
    for (int off = 32; off; off >>= 1) acc += __shfl_xor(acc, off, 64);
    if (lane == 0) out1[b * 256 + t] = acc + eb1[t];
}

// ---------------- Kernel 3b: middle chain (identical to R6) ----------------
__device__ __forceinline__ float block_sum256(float x, float* red) {
    const int t = threadIdx.x;
    red[t] = x;
    __syncthreads();
    for (int s = 128; s > 0; s >>= 1) {
        if (t < s) red[t] += red[t + s];
        __syncthreads();
    }
    const float r = red[0];
    __syncthreads();
    return r;
}

__global__ __launch_bounds__(256) void mlp_middle(
    const float* __restrict__ out1, const float* __restrict__ gu,
    const float* __restrict__ g1,  const float* __restrict__ bb1,
    const float* __restrict__ ew2, const float* __restrict__ eb2,
    const float* __restrict__ emb_tab,
    const float* __restrict__ dw1, const float* __restrict__ db1,
    const float* __restrict__ g2,  const float* __restrict__ bb2,
    float* __restrict__ hs2) {
    __shared__ float red[256];
    __shared__ float hs[256];
    __shared__ float es[LSYM * EMB];

    const int b = blockIdx.x;
    const int t = threadIdx.x;

    float acc = out1[b * 256 + t];
    {
        const float m = block_sum256(acc, red) * (1.0f / 256.0f);
        const float d = acc - m;
        const float v = block_sum256(d * d, red) * (1.0f / 256.0f);
        float x = d * rsqrtf(v + 1e-5f) * g1[t] + bb1[t];
        x = 0.5f * x * (1.0f + erff(x * 0.70710678118654752f));
        hs[t] = x;
    }
    __syncthreads();

    float z;
    {
        float a2 = eb2[t];
        const float* w2row = ew2 + t * 256;
        for (int k = 0; k < 256; k += 4) {
            const float4 w = *reinterpret_cast<const float4*>(w2row + k);
            a2 += w.x * hs[k] + w.y * hs[k + 1] + w.z * hs[k + 2] + w.w * hs[k + 3];
        }
        const float u = gu[b * 256 + t];
        z = a2 - logf(-logf(u));
    }

    {
        int   bi = t & 31;
        float bz = z;
        for (int off = 16; off; off >>= 1) {
            const float oz = __shfl_xor(bz, off, 32);
            const int   oi = __shfl_xor(bi, off, 32);
            if (oz > bz || (oz == bz && oi < bi)) { bz = oz; bi = oi; }
        }
        const int l = t >> 5, v32 = t & 31;
        es[l * EMB + v32]      = emb_tab[bi * EMB + v32];
        es[l * EMB + 32 + v32] = emb_tab[bi * EMB + 32 + v32];
    }
    __syncthreads();

    float a3 = db1[t];
    {
        const float* d1row = dw1 + t * (LSYM * EMB);
        for (int k = 0; k < LSYM * EMB; k += 4) {
            const float4 w = *reinterpret_cast<const float4*>(d1row + k);
            a3 += w.x * es[k] + w.y * es[k + 1] + w.z * es[k + 2] + w.w * es[k + 3];
        }
    }
    {
        const float m2 = block_sum256(a3, red) * (1.0f / 256.0f);
        const float dd = a3 - m2;
        const float vv = block_sum256(dd * dd, red) * (1.0f / 256.0f);
        float y = dd * rsqrtf(vv + 1e-5f) * g2[t] + bb2[t];
        y = 0.5f * y * (1.0f + erff(y * 0.70710678118654752f));
        hs2[b * 256 + t] = y;
    }
}

// ---------------- Kernel 3c: dec layer 2 matvec (identical to R6) ----------------
__global__ __launch_bounds__(256) void dec2_matvec(const float* __restrict__ hs2,
                                                   const float* __restrict__ dw2,
                                                   const float* __restrict__ db2,
                                                   float* __restrict__ dec_sc) {
    const int wv   = (blockIdx.x * 256 + threadIdx.x) >> 6;
    const int lane = threadIdx.x & 63;
    const int b = wv >> 11, j = wv & 2047;
    const float4 w = reinterpret_cast<const float4*>(dw2 + (size_t)j * 256)[lane];
    const float4 h = reinterpret_cast<const float4*>(hs2 + b * 256)[lane];
    float acc = w.x * h.x + w.y * h.y + w.z * h.z + w.w * h.w;
    for (int off = 32; off; off >>= 1) acc += __shfl_xor(acc, off, 64);
    if (lane == 0) dec_sc[b * 2048 + j] = 0.1f * (acc + db2[j]);
}

// ---------------- Kernel 4: residual add — nt load hid, nt store out, 4096 blocks ----------------
__global__ __launch_bounds__(256) void residual_add(const float* __restrict__ hid,
                                                    const float* __restrict__ dec,
                                                    float* __restrict__ out) {
    const size_t tid0 = (size_t)blockIdx.x * 256 + threadIdx.x;   // < 2^20
    const int h4 = (int)(tid0 & (H / 4 - 1));
    const f32x4* __restrict__ hv4 = reinterpret_cast<const f32x4*>(hid);
    const float4* __restrict__ dv4 = reinterpret_cast<const float4*>(dec);
    f32x4* __restrict__ ov4 = reinterpret_cast<f32x4*>(out);
    size_t i = tid0;
#pragma unroll
    for (int b = 0; b < B; ++b) {
        const float4 dv = dv4[b * (H / 4) + h4];
        const f32x4 dvv = {dv.x, dv.y, dv.z, dv.w};
#pragma unroll
        for (int r = 0; r < 2; ++r, i += (size_t)1 << 20) {
            const f32x4 hv = __builtin_nontemporal_load(&hv4[i]);
            const f32x4 o = hv + dvv;
            __builtin_nontemporal_store(o, &ov4[i]);
        }
    }
}

extern "C" void kernel_launch(void* const* d_in, const int* in_sizes, int n_in,
                              void* d_out, int out_size, void* d_ws, size_t ws_size,
                              hipStream_t stream) {
    const float* hid   = (const float*)d_in[0];
    const float* gu    = (const float*)d_in[1];
    const float* ew1   = (const float*)d_in[2];
    const float* eb1   = (const float*)d_in[3];
    const float* g1    = (const float*)d_in[4];
    const float* bb1   = (const float*)d_in[5];
    const float* ew2   = (const float*)d_in[6];
    const float* eb2   = (const float*)d_in[7];
    const float* emb   = (const float*)d_in[8];
    const float* dw1   = (const float*)d_in[9];
    const float* db1   = (const float*)d_in[10];
    const float* g2    = (const float*)d_in[11];
    const float* bb2   = (const float*)d_in[12];
    const float* dw2   = (const float*)d_in[13];
    const float* db2   = (const float*)d_in[14];
    float* out = (float*)d_out;

    // workspace: [ part: SPLIT*B*H (4 MiB) | pooled: B*H | dec_sc: B*H | out1: B*256 | hs2: B*256 ]
    float* part   = (float*)d_ws;
    float* pooled = part + (size_t)SPLIT * B * H;
    float* dec_sc = pooled + (size_t)B * H;
    float* out1   = dec_sc + (size_t)B * H;
    float* hs2    = out1 + (size_t)B * 256;

    pool_partial<<<dim3(SPLIT, B), 256, 0, stream>>>(hid, part);
    pool_reduce<<<(B * H / 4 + 255) / 256, 256, 0, stream>>>(part, pooled);
    enc1_matvec<<<B * 256 / 4, 256, 0, stream>>>(pooled, ew1, eb1, out1);
    mlp_middle<<<B, 256, 0, stream>>>(out1, gu, g1, bb1, ew2, eb2, emb,
                                      dw1, db1, g2, bb2, hs2);
    dec2_matvec<<<B * 2048 / 4, 256, 0, stream>>>(hs2, dw2, db2, dec_sc);
    residual_add<<<4096, 256, 0, stream>>>(hid, dec_sc, out);
}